// Round 12
// baseline (128.440 us; speedup 1.0000x reference)
//
#include <hip/hip_runtime.h>
#include <hip/hip_bf16.h>
#include <cstdint>

typedef __attribute__((ext_vector_type(4))) float f32x4;
typedef __attribute__((ext_vector_type(8))) short s16x8;

#define NB   32
#define NL   2048
#define NH   512
#define NM   (NB * NL)          // 65536 rows
#define SCALE 0.04419417382415922f  // 1/sqrt(512)

__device__ __forceinline__ ushort f2bf(float f) {
    __hip_bfloat16 b = __float2bfloat16(f);   // pairs fuse into v_cvt_pk_bf16_f32
    return *reinterpret_cast<ushort*>(&b);
}
__device__ __forceinline__ unsigned long long pack4(float4 f) {
    union { ushort u[4]; unsigned long long v; } p;
    p.u[0] = f2bf(f.x); p.u[1] = f2bf(f.y); p.u[2] = f2bf(f.z); p.u[3] = f2bf(f.w);
    return p.v;
}

// async global->LDS, 16B/lane: dest = wave-uniform base + lane*16; global addr per-lane
#define GL16(g, l)                                                         \
    __builtin_amdgcn_global_load_lds(                                      \
        (const __attribute__((address_space(1))) unsigned int*)(g),        \
        (__attribute__((address_space(3))) unsigned int*)(l), 16, 0, 0)

// ============================================================================
// k_pre: convW (blocks 0..63) + eq (blocks 64..95)
// ============================================================================
__global__ __launch_bounds__(256) void k_pre(const float* __restrict__ W,
                                             ushort* __restrict__ Wb,
                                             const float* __restrict__ query,
                                             const float* __restrict__ Wq,
                                             float* __restrict__ eq) {
    int bid = blockIdx.x;
    int t = threadIdx.x;
    if (bid < 64) {
        const float4* F = (const float4*)W;
        unsigned long long* U = (unsigned long long*)Wb;
        int base = bid * 1024 + t;
        float4 f[4];
#pragma unroll
        for (int k = 0; k < 4; ++k) f[k] = F[base + k * 256];
#pragma unroll
        for (int k = 0; k < 4; ++k) U[base + k * 256] = pack4(f[k]);
    } else {
        __shared__ float q[NH];
        int b = bid - 64;
        q[t] = query[b * NH + t];
        q[t + 256] = query[b * NH + t + 256];
        __syncthreads();
#pragma unroll
        for (int half = 0; half < 2; ++half) {
            int o = t + half * 256;
            const float4* w = (const float4*)(Wq + (size_t)o * NH);
            float acc = 0.f;
#pragma unroll 4
            for (int i = 0; i < NH / 4; ++i) {
                float4 x = w[i];
                acc += q[4 * i] * x.x + q[4 * i + 1] * x.y + q[4 * i + 2] * x.z + q[4 * i + 3] * x.w;
            }
            eq[b * NH + o] = acc;
        }
    }
}

// ============================================================================
// k_gemm_full v4: 1024 blocks x 256 thr (4 waves).
// BM=64, BN=512, BK=32, 16 K-steps. Wave tile 64 rows x 128 cols.
// A staged as BF16 via reg-path (cvt ONCE per element on write side; was 4x
// on read side in v3 -- the dominant VALU cost). B staged via gl16 with
// pre-swizzled global source; both A and B use chunk ^= (row&3) XOR swizzle.
// LDS 72 KB -> 2 blocks/CU. Counted-vmcnt schedule: A-reg loads 1 phase ahead,
// B gl16 2 phases ahead, vmcnt(8) steady state (A issues before B per phase).
// ============================================================================
__global__ __launch_bounds__(256, 2) void k_gemm_full(const float* __restrict__ ref,
                                                      const ushort* __restrict__ Wb,
                                                      const float* __restrict__ eq,
                                                      const float* __restrict__ v,
                                                      const int* __restrict__ mask,
                                                      float* __restrict__ out_sc) {
    __shared__ char smem[73728];                 // 72 KB -> 2 blocks/CU
    ushort* Bs0 = (ushort*)smem;                 // 32 KB [512][32] bf16
    ushort* Bs1 = (ushort*)(smem + 32768);       // 32 KB
    ushort* As0 = (ushort*)(smem + 65536);       // 4 KB  [64][32] bf16
    ushort* As1 = (ushort*)(smem + 69632);       // 4 KB

    int tid = threadIdx.x;
    int lane = tid & 63, wid = tid >> 6;         // 4 waves
    int blk = blockIdx.x;
    int m0g = blk << 6;                          // 64 rows/block
    int b = blk >> 5;                            // batch

    f32x4 acc[4][8];
#pragma unroll
    for (int i = 0; i < 4; ++i)
#pragma unroll
        for (int j = 0; j < 8; ++j) acc[i][j] = (f32x4)(0.f);

    // ---- B staging: wave stages B rows wid*128..+128, pre-swizzled chunk ----
    const ushort* bglob = Wb + ((size_t)(wid * 128) + (lane >> 2)) * NH
                             + ((((lane & 3) ^ ((lane >> 2) & 3))) << 3);
    // ---- A staging (reg path): thread t: row t>>2, logical chunk t&3 ----
    int arow = tid >> 2, acl = tid & 3;
    const float* aglob = ref + (size_t)(m0g + arow) * NH + acl * 8;
    int awr = arow * 32 + ((acl ^ (arow & 3)) << 3);   // swizzled ds_write (ushort idx)

    int lr = lane & 15, kq = lane >> 4;
    int bbase = (wid * 128 + lr) * 32 + ((kq ^ (lr & 3)) << 3);   // + fc*512
    int abase = lr * 32 + ((kq ^ (lr & 3)) << 3);                 // + fr*512

    float4 qa0, qa1;     // A prefetch regs (K-step k+1)

#define LOAD_A(kt)                                              \
    {   qa0 = *(const float4*)(aglob + (kt) * 32);              \
        qa1 = *(const float4*)(aglob + (kt) * 32 + 4); }

#define WRITE_A(Asb)                                            \
    {   union { ushort u[8]; s16x8 v; } p;                      \
        p.u[0] = f2bf(qa0.x); p.u[1] = f2bf(qa0.y);             \
        p.u[2] = f2bf(qa0.z); p.u[3] = f2bf(qa0.w);             \
        p.u[4] = f2bf(qa1.x); p.u[5] = f2bf(qa1.y);             \
        p.u[6] = f2bf(qa1.z); p.u[7] = f2bf(qa1.w);             \
        *(s16x8*)&(Asb)[awr] = p.v; }

#define STAGE_B(Bsb, kt)                                        \
    {   _Pragma("unroll")                                       \
        for (int j = 0; j < 8; ++j)                             \
            GL16(bglob + (kt) * 32 + j * 16 * NH,               \
                 (Bsb) + (wid * 128 + j * 16) * 32); }

#define READ_FRAGS(Bsb, Asb)                                                     \
    _Pragma("unroll")                                                            \
    for (int f = 0; f < 4; ++f) af[f] = *(const s16x8*)&(Asb)[abase + f * 512];  \
    _Pragma("unroll")                                                            \
    for (int f = 0; f < 8; ++f) bfr[f] = *(const s16x8*)&(Bsb)[bbase + f * 512];

#define MFMA_ALL()                                                               \
    __builtin_amdgcn_s_setprio(1);                                               \
    _Pragma("unroll")                                                            \
    for (int fr = 0; fr < 4; ++fr)                                               \
        _Pragma("unroll")                                                        \
        for (int fc = 0; fc < 8; ++fc)                                           \
            acc[fr][fc] = __builtin_amdgcn_mfma_f32_16x16x32_bf16(               \
                af[fr], bfr[fc], acc[fr][fc], 0, 0, 0);                          \
    __builtin_amdgcn_s_setprio(0);

    // ---- prologue ----
    // issue order: A(0) 2, A(1) 2, B(0) 8, B(1) 8  -> 20 outstanding
    LOAD_A(0)
    float4 ra0 = qa0, ra1 = qa1;    // keep A(0) in separate regs
    LOAD_A(1)
    STAGE_B(Bs0, 0)
    STAGE_B(Bs1, 1)
    asm volatile("s_waitcnt vmcnt(18)" ::: "memory");   // A(0) done
    {   // synchronous cvt+write A(0) -> buf0
        union { ushort u[8]; s16x8 v; } p;
        p.u[0] = f2bf(ra0.x); p.u[1] = f2bf(ra0.y);
        p.u[2] = f2bf(ra0.z); p.u[3] = f2bf(ra0.w);
        p.u[4] = f2bf(ra1.x); p.u[5] = f2bf(ra1.y);
        p.u[6] = f2bf(ra1.z); p.u[7] = f2bf(ra1.w);
        *(s16x8*)&As0[awr] = p.v;
    }
    asm volatile("s_waitcnt lgkmcnt(0)" ::: "memory");
    __builtin_amdgcn_s_barrier();

    // ---- main loop: phases k=0..13 ----
#pragma unroll 1
    for (int t2 = 0; t2 < 7; ++t2) {
        {   // phase A: k=2*t2 from buf0; write A(k+1)->buf1; issue k+2 into buf0
            s16x8 bfr[8], af[4];
            asm volatile("s_waitcnt vmcnt(8)" ::: "memory");
            __builtin_amdgcn_s_barrier();
            READ_FRAGS(Bs0, As0)
            WRITE_A(As1)
            asm volatile("s_waitcnt lgkmcnt(0)" ::: "memory");
            __builtin_amdgcn_sched_barrier(0);
            __builtin_amdgcn_s_barrier();
            LOAD_A(2 * t2 + 2)
            STAGE_B(Bs0, 2 * t2 + 2)
            MFMA_ALL()
        }
        {   // phase B: k=2*t2+1 from buf1; write A(k+1)->buf0; issue k+3 into buf1
            s16x8 bfr[8], af[4];
            asm volatile("s_waitcnt vmcnt(8)" ::: "memory");
            __builtin_amdgcn_s_barrier();
            READ_FRAGS(Bs1, As1)
            WRITE_A(As0)
            asm volatile("s_waitcnt lgkmcnt(0)" ::: "memory");
            __builtin_amdgcn_sched_barrier(0);
            __builtin_amdgcn_s_barrier();
            LOAD_A(2 * t2 + 3)
            STAGE_B(Bs1, 2 * t2 + 3)
            MFMA_ALL()
        }
    }
    {   // phase k=14: no new issue; write A(15)->buf1
        s16x8 bfr[8], af[4];
        asm volatile("s_waitcnt vmcnt(8)" ::: "memory");
        __builtin_amdgcn_s_barrier();
        READ_FRAGS(Bs0, As0)
        WRITE_A(As1)
        asm volatile("s_waitcnt lgkmcnt(0)" ::: "memory");
        __builtin_amdgcn_sched_barrier(0);
        __builtin_amdgcn_s_barrier();
        MFMA_ALL()
    }
    {   // phase k=15: final drain
        s16x8 bfr[8], af[4];
        asm volatile("s_waitcnt vmcnt(0)" ::: "memory");
        __builtin_amdgcn_s_barrier();
        READ_FRAGS(Bs1, As1)
        MFMA_ALL()
    }
#undef LOAD_A
#undef WRITE_A
#undef STAGE_B
#undef READ_FRAGS
#undef MFMA_ALL

    __syncthreads();                             // before sc_red overlay

    // ---- epilogue: full score rows (sc_red overlays smem) ----
    float* sc_red = (float*)smem;                // [4][64]
    const float* eqb = eq + b * NH;
    float vv[8], ee[8];
#pragma unroll
    for (int fc = 0; fc < 8; ++fc) {
        int c = wid * 128 + fc * 16 + lr;
        vv[fc] = v[c];
        ee[fc] = eqb[c];
    }
#pragma unroll
    for (int fr = 0; fr < 4; ++fr) {
#pragma unroll
        for (int reg = 0; reg < 4; ++reg) {
            float s = 0.f;
#pragma unroll
            for (int fc = 0; fc < 8; ++fc) {
                float x = acc[fr][fc][reg] + ee[fc];
                float t = 1.f - 2.f / (__expf(2.f * x) + 1.f);  // tanh
                s += vv[fc] * t;
            }
            s += __shfl_xor(s, 1);
            s += __shfl_xor(s, 2);
            s += __shfl_xor(s, 4);
            s += __shfl_xor(s, 8);
            if (lr == 0) sc_red[wid * 64 + fr * 16 + kq * 4 + reg] = s;
        }
    }
    __syncthreads();
    if (tid < 64) {
        float t = 0.f;
#pragma unroll
        for (int w = 0; w < 4; ++w) t += sc_red[w * 64 + tid];
        t *= SCALE;
        int rg = m0g + tid;
        if (mask[rg] != 0) t = -1e9f;
        out_sc[rg] = t;
    }
}

// ============================================================================
// k_smglp: softmax (from final scores) + glimpse slice. grid (16 sp, 32 b).
// ============================================================================
__global__ __launch_bounds__(256) void k_smglp(const float* __restrict__ scores,
                                               const float* __restrict__ ref,
                                               float* __restrict__ glp) {
    int sp = blockIdx.x, b = blockIdx.y;
    int tid = threadIdx.x;
    int lane = tid & 63, wid = tid >> 6;
    __shared__ float red[4];
    __shared__ float asl[128];    // unnormalized exp for rows sp*128..+128
    float sc[8];
    float mx = -3.4e38f;
#pragma unroll
    for (int i = 0; i < 8; ++i) {
        sc[i] = scores[b * NL + i * 256 + tid];
        mx = fmaxf(mx, sc[i]);
    }
#pragma unroll
    for (int o = 32; o >= 1; o >>= 1) mx = fmaxf(mx, __shfl_xor(mx, o));
    if (lane == 0) red[wid] = mx;
    __syncthreads();
    mx = fmaxf(fmaxf(red[0], red[1]), fmaxf(red[2], red[3]));
    __syncthreads();
    float ls = 0.f;
#pragma unroll
    for (int i = 0; i < 8; ++i) {
        float e = __expf(sc[i] - mx);
        ls += e;
        if (i == (sp >> 1) && (tid >> 7) == (sp & 1)) asl[tid & 127] = e;
    }
#pragma unroll
    for (int o = 32; o >= 1; o >>= 1) ls += __shfl_xor(ls, o);
    if (lane == 0) red[wid] = ls;
    __syncthreads();
    float inv = 1.f / (red[0] + red[1] + red[2] + red[3]);

    const float* rb = ref + ((size_t)b * NL + sp * 128) * NH;
    float2 acc = make_float2(0.f, 0.f);
#pragma unroll 4
    for (int l = 0; l < 128; ++l) {
        float a = asl[l];
        float2 r = ((const float2*)(rb + (size_t)l * NH))[tid];
        acc.x += a * r.x;
        acc.y += a * r.y;
    }
    acc.x *= inv;
    acc.y *= inv;
    ((float2*)(glp + (size_t)(sp * NB + b) * NH))[tid] = acc;
}

// ---- reduce glimpse partials (16 splits) ----
__global__ __launch_bounds__(256) void k_gred(const float* __restrict__ glp,
                                              float* __restrict__ out_gl) {
    int idx = blockIdx.x * 256 + threadIdx.x;   // 16384 = B*H
    float s = 0.f;
#pragma unroll
    for (int sp = 0; sp < 16; ++sp) s += glp[sp * (NB * NH) + idx];
    out_gl[idx] = s;
}

extern "C" void kernel_launch(void* const* d_in, const int* in_sizes, int n_in,
                              void* d_out, int out_size, void* d_ws, size_t ws_size,
                              hipStream_t stream) {
    const float* query = (const float*)d_in[0];
    const float* ref   = (const float*)d_in[1];
    const int*   mask  = (const int*)d_in[2];
    const float* W_ref = (const float*)d_in[3];
    const float* W_q   = (const float*)d_in[4];
    const float* v     = (const float*)d_in[5];

    float* out_gl = (float*)d_out;              // 32*512
    float* out_sc = out_gl + NB * NH;           // 32*2048 (final scores)

    char* w = (char*)d_ws;
    ushort* wW = (ushort*)w;                    // 524,288 B @ 0
    float* eq  = (float*)(w + 524288);          // 65,536 B
    float* glp = (float*)(w + 589824);          // 16*32*512*4 = 1,048,576 B

    k_pre<<<96, 256, 0, stream>>>(W_ref, wW, query, W_q, eq);
    k_gemm_full<<<1024, 256, 0, stream>>>(ref, wW, eq, v, mask, out_sc);
    k_smglp<<<dim3(16, NB), 256, 0, stream>>>(out_sc, ref, glp);
    k_gred<<<64, 256, 0, stream>>>(glp, out_gl);
}